// Round 2
// baseline (551.256 us; speedup 1.0000x reference)
//
#include <hip/hip_runtime.h>
#include <stdint.h>

// Cross-attention fused block, MI355X/gfx950.
// Round 2: identical audited compute path to round 1 (bf16 MFMA GEMMs with
// global_load_lds + XOR-swizzled LDS; flash attention with swapped QK^T and
// in-register P shuffle). NEW: mask dtype is detected on-device (int32 vs
// int8/bool) and bit-packed to a u64 bitmask -- removes the OOB-read risk of
// assuming int32 and cuts attention mask traffic to 8 MB total.

#define H_ 8
#define N_ 4096
#define M_ 4096
#define F_ 1024
#define D_ 256

typedef unsigned short u16;
typedef unsigned int u32;
typedef unsigned long long u64;
typedef __bf16 bf16x8 __attribute__((ext_vector_type(8)));
typedef float f32x4 __attribute__((ext_vector_type(4)));

static __device__ __forceinline__ u16 f2bf(float f) {
  union { float f; u32 u; } v; v.f = f;
  u32 u = v.u + 0x7fffu + ((v.u >> 16) & 1u);
  return (u16)(u >> 16);
}

static __device__ __forceinline__ void gld16(const void* g, void* l) {
  __builtin_amdgcn_global_load_lds(
      (const __attribute__((address_space(1))) void*)g,
      (__attribute__((address_space(3))) void*)l, 16, 0, 0);
}

// ---------------- mask dtype detect + bit-pack ----------------
// If mask arrived as int32 (0/1), every 4-byte word is 0 or 1. If it arrived
// as int8/bool, the first 16 KB of random 0/1 bytes will certainly contain a
// word with a byte set above bit 0. flag=0 -> int32, flag=1 -> int8.
__global__ void k_mask_detect(const u32* __restrict__ m, u32* __restrict__ flag) {
  u32 bad = 0;
  for (int i = threadIdx.x; i < 4096; i += 64) bad |= (m[i] & ~1u);
  u64 anyBad = __ballot(bad != 0);
  if (threadIdx.x == 0) *flag = (anyBad != 0) ? 1u : 0u;
}

// One u64 (64 mask bits) per thread. Reads int32 or int8 source per *flag.
__global__ void k_mask_pack(const void* __restrict__ mp, const u32* __restrict__ flag,
                            u64* __restrict__ out) {
  const int i = blockIdx.x * 256 + threadIdx.x;
  u64 bits = 0;
  if (*flag) {  // int8 / bool source
    const u32* p = (const u32*)mp + (size_t)i * 16;
#pragma unroll
    for (int w = 0; w < 16; ++w) {
      u32 x = p[w];
#pragma unroll
      for (int j = 0; j < 4; ++j)
        bits |= (u64)(((x >> (8 * j)) & 0xffu) ? 1u : 0u) << (w * 4 + j);
    }
  } else {      // int32 source
    const u32* p = (const u32*)mp + (size_t)i * 64;
#pragma unroll
    for (int w = 0; w < 64; ++w) bits |= (u64)(p[w] ? 1u : 0u) << w;
  }
  out[i] = bits;
}

// ---------------- f32 -> bf16 elementwise (vectorized) ----------------
__global__ void k_f32_to_bf16(const float* __restrict__ in, u16* __restrict__ out, int n4) {
  int i = blockIdx.x * blockDim.x + threadIdx.x;
  if (i >= n4) return;
  float4 v = ((const float4*)in)[i];
  u32 w0 = (u32)f2bf(v.x) | ((u32)f2bf(v.y) << 16);
  u32 w1 = (u32)f2bf(v.z) | ((u32)f2bf(v.w) << 16);
  ((uint2*)out)[i] = make_uint2(w0, w1);
}

// ------------- transpose-convert f32 [b][R][C] -> bf16 [b][C][R] -------------
__global__ void k_transpose_f32_bf16(const float* __restrict__ in, u16* __restrict__ out,
                                     int R, int C) {
  __shared__ float t[32][33];
  const int b = blockIdx.z;
  const float* src = in + (size_t)b * R * C;
  u16* dst = out + (size_t)b * R * C;
  const int r0 = blockIdx.x * 32, c0 = blockIdx.y * 32;
  const int tr = threadIdx.x >> 3, tc = (threadIdx.x & 7) * 4;
  float4 v = *(const float4*)(src + (size_t)(r0 + tr) * C + c0 + tc);
  t[tr][tc + 0] = v.x; t[tr][tc + 1] = v.y; t[tr][tc + 2] = v.z; t[tr][tc + 3] = v.w;
  __syncthreads();
  u16* d4 = dst + (size_t)(c0 + tr) * R + r0 + tc;
  d4[0] = f2bf(t[tc + 0][tr]); d4[1] = f2bf(t[tc + 1][tr]);
  d4[2] = f2bf(t[tc + 2][tr]); d4[3] = f2bf(t[tc + 3][tr]);
}

// ------------- transpose bf16 [b][R][C] -> bf16 [b][C][R] -------------
__global__ void k_transpose_bf16(const u16* __restrict__ in, u16* __restrict__ out,
                                 int R, int C) {
  __shared__ u16 t[32][33];
  const int b = blockIdx.z;
  const u16* src = in + (size_t)b * R * C;
  u16* dst = out + (size_t)b * R * C;
  const int r0 = blockIdx.x * 32, c0 = blockIdx.y * 32;
  const int tr = threadIdx.x >> 3, tc = (threadIdx.x & 7) * 4;
  const u16* s4 = src + (size_t)(r0 + tr) * C + c0 + tc;
  t[tr][tc + 0] = s4[0]; t[tr][tc + 1] = s4[1]; t[tr][tc + 2] = s4[2]; t[tr][tc + 3] = s4[3];
  __syncthreads();
  u16* d4 = dst + (size_t)(c0 + tr) * R + r0 + tc;
  d4[0] = t[tc + 0][tr]; d4[1] = t[tc + 1][tr]; d4[2] = t[tc + 2][tr]; d4[3] = t[tc + 3][tr];
}

// ---------------- NT GEMM: C[row][col] = sum_k A[row][k]*Bt[col][k] ----------------
// 128x128 tile, BK=64, 4 waves (2x2), 16x16x32 bf16 MFMA, global_load_lds + XOR swizzle.
// EPI 0: Cb = bf16(acc + bias[col]);  EPI 1: Cf = acc + bias[col] + resid[row][col]
template <int EPI>
__global__ __launch_bounds__(256, 2) void k_gemm_nt(
    const u16* __restrict__ A, const u16* __restrict__ B,
    const float* __restrict__ bias, const float* __restrict__ resid,
    u16* __restrict__ Cb, float* __restrict__ Cf,
    int K, int lda, int ldb, int ldc,
    size_t aBatch, size_t bBatch, size_t biasBatch, size_t cBatch)
{
  __shared__ u16 la[128 * 64];
  __shared__ u16 lb[128 * 64];
  const int tid = threadIdx.x;
  const int lane = tid & 63, wave = tid >> 6;
  const int g = lane >> 4, fr = lane & 15;
  const int wr = wave >> 1, wc = wave & 1;
  const int z = blockIdx.z;
  const size_t row0 = (size_t)blockIdx.x * 128, col0 = (size_t)blockIdx.y * 128;
  const u16* Ab = A + z * aBatch + row0 * lda;
  const u16* Bb = B + z * bBatch + col0 * ldb;

  f32x4 zero = {0.f, 0.f, 0.f, 0.f};
  f32x4 acc[4][4];
#pragma unroll
  for (int m = 0; m < 4; ++m)
#pragma unroll
    for (int n = 0; n < 4; ++n) acc[m][n] = zero;

  for (int k0 = 0; k0 < K; k0 += 64) {
    __syncthreads();
#pragma unroll
    for (int i = 0; i < 4; ++i) {
      int c = i * 256 + tid;
      int row = c >> 3, slot = c & 7;
      int srcSlot = slot ^ (row & 7);
      gld16(Ab + (size_t)row * lda + k0 + srcSlot * 8, la + (size_t)(i * 256 + wave * 64) * 8);
      gld16(Bb + (size_t)row * ldb + k0 + srcSlot * 8, lb + (size_t)(i * 256 + wave * 64) * 8);
    }
    __syncthreads();
#pragma unroll
    for (int kk = 0; kk < 2; ++kk) {
      const int colByte = (kk * 32 + g * 8) * 2;
      bf16x8 af[4], bfr[4];
#pragma unroll
      for (int m = 0; m < 4; ++m) {
        int row = wr * 64 + m * 16 + fr;
        af[m] = *(const bf16x8*)((const char*)la + ((row * 128 + colByte) ^ ((row & 7) << 4)));
      }
#pragma unroll
      for (int n = 0; n < 4; ++n) {
        int row = wc * 64 + n * 16 + fr;
        bfr[n] = *(const bf16x8*)((const char*)lb + ((row * 128 + colByte) ^ ((row & 7) << 4)));
      }
#pragma unroll
      for (int m = 0; m < 4; ++m)
#pragma unroll
        for (int n = 0; n < 4; ++n)
          acc[m][n] = __builtin_amdgcn_mfma_f32_16x16x32_bf16(af[m], bfr[n], acc[m][n], 0, 0, 0);
    }
  }

#pragma unroll
  for (int n = 0; n < 4; ++n) {
    const int col = wc * 64 + n * 16 + fr;
    const float bv = bias[z * biasBatch + col0 + col];
#pragma unroll
    for (int m = 0; m < 4; ++m) {
#pragma unroll
      for (int r = 0; r < 4; ++r) {
        const int row = wr * 64 + m * 16 + g * 4 + r;
        const float val = acc[m][n][r] + bv;
        const size_t idx = z * cBatch + (row0 + row) * ldc + col0 + col;
        if (EPI == 0) {
          Cb[idx] = f2bf(val);
        } else {
          Cf[idx] = val + resid[(row0 + row) * ldc + col0 + col];
        }
      }
    }
  }
}

// ---------------- flash attention ----------------
// grid (N/64, H), 256 threads (4 waves x 16 q-rows). Swapped QK^T: s'[m][n]=mfma(K,q).
// K tile [64][256] and V^T tile [256][64] LDS-staged with XOR swizzle.
// Lane (g=lane>>4, fr=lane&15) holds s'[m= mt*16+g*4+r][n=fr]; softmax state lane-local in n.
__global__ __launch_bounds__(256, 2) void k_attn(
    const u16* __restrict__ q, const u16* __restrict__ k,
    const u16* __restrict__ vt, const u64* __restrict__ mbits,
    u16* __restrict__ cat)
{
  __shared__ u16 smem[32768];          // 64KB: lk 32KB + lv 32KB (lt aliases after loop)
  u16* lk = smem;                      // [64 m][256 d] swizzled
  u16* lv = smem + 16384;              // [256 d][64 m] swizzled
  const int tid = threadIdx.x;
  const int lane = tid & 63, wave = tid >> 6;
  const int g = lane >> 4, fr = lane & 15;
  const int h = blockIdx.y;
  const int n0 = blockIdx.x * 64 + wave * 16;   // this wave's first q-row
  const u16* qh = q + ((size_t)h * N_ + n0 + fr) * D_;
  const u16* kh = k + (size_t)h * M_ * D_;
  const u16* vh = vt + (size_t)h * D_ * M_;

  bf16x8 qf[8];
#pragma unroll
  for (int dc = 0; dc < 8; ++dc) qf[dc] = *(const bf16x8*)(qh + dc * 32 + g * 8);

  f32x4 zero = {0.f, 0.f, 0.f, 0.f};
  f32x4 racc[16];                      // r'[d=dt*16+g*4+r][n=fr]
#pragma unroll
  for (int i = 0; i < 16; ++i) racc[i] = zero;
  float mrow = -3e38f, lrow = 0.f;

  const u64* mrp = mbits + (size_t)(n0 + fr) * (M_ / 64);
  const bool useMask = (h >= 4);

  for (int m0 = 0; m0 < M_; m0 += 64) {
    __syncthreads();
#pragma unroll
    for (int i = 0; i < 8; ++i) {
      int c = i * 256 + tid;
      int row = c >> 5, slot = c & 31;                 // K: 32 chunks/row
      int srcSlot = (slot & 24) | ((slot ^ row) & 7);
      gld16(kh + (size_t)(m0 + row) * D_ + srcSlot * 8, lk + (size_t)(i * 256 + wave * 64) * 8);
      int row2 = c >> 3, slot2 = c & 7;                // V: 8 chunks/row
      int srcSlot2 = (slot2 ^ row2) & 7;
      gld16(vh + (size_t)row2 * M_ + m0 + srcSlot2 * 8, lv + (size_t)(i * 256 + wave * 64) * 8);
    }
    __syncthreads();

    // s' = K . q^T  (A = K rows from LDS, B = q frags in regs)
    f32x4 s[4];
#pragma unroll
    for (int mt = 0; mt < 4; ++mt) s[mt] = zero;
#pragma unroll
    for (int dc = 0; dc < 8; ++dc) {
      const int colByte = (dc * 32 + g * 8) * 2;
#pragma unroll
      for (int mt = 0; mt < 4; ++mt) {
        const int row = mt * 16 + fr;
        bf16x8 af = *(const bf16x8*)((const char*)lk + ((row * 512 + colByte) ^ ((row & 7) << 4)));
        s[mt] = __builtin_amdgcn_mfma_f32_16x16x32_bf16(af, qf[dc], s[mt], 0, 0, 0);
      }
    }

    if (useMask) {
      const u64 wm = mrp[m0 >> 6];
#pragma unroll
      for (int mt = 0; mt < 4; ++mt) {
        const u32 nib = (u32)(wm >> (mt * 16 + g * 4));
        if (!(nib & 1u)) s[mt][0] -= 1e9f;
        if (!(nib & 2u)) s[mt][1] -= 1e9f;
        if (!(nib & 4u)) s[mt][2] -= 1e9f;
        if (!(nib & 8u)) s[mt][3] -= 1e9f;
      }
    }

    // online softmax (row n = fr; values spread over lanes fr, fr+16, fr+32, fr+48)
    float pm = -3e38f;
#pragma unroll
    for (int mt = 0; mt < 4; ++mt)
#pragma unroll
      for (int r = 0; r < 4; ++r) pm = fmaxf(pm, s[mt][r]);
    pm = fmaxf(pm, __shfl_xor(pm, 16, 64));
    pm = fmaxf(pm, __shfl_xor(pm, 32, 64));
    const float mnew = fmaxf(mrow, pm);
    const float scale = __expf(mrow - mnew);
    float ls = 0.f;
#pragma unroll
    for (int mt = 0; mt < 4; ++mt)
#pragma unroll
      for (int r = 0; r < 4; ++r) { float p = __expf(s[mt][r] - mnew); s[mt][r] = p; ls += p; }
    ls += __shfl_xor(ls, 16, 64);
    ls += __shfl_xor(ls, 32, 64);
    lrow = lrow * scale + ls;
    mrow = mnew;
#pragma unroll
    for (int i = 0; i < 16; ++i) racc[i] *= scale;

    // pack P (bf16 pairs) and redistribute to PV B-operand layout via shuffles
    u32 w[4][2];
#pragma unroll
    for (int mt = 0; mt < 4; ++mt) {
      w[mt][0] = (u32)f2bf(s[mt][0]) | ((u32)f2bf(s[mt][1]) << 16);
      w[mt][1] = (u32)f2bf(s[mt][2]) | ((u32)f2bf(s[mt][3]) << 16);
    }
    const int src0 = (g & 1) * 32 + fr;
    const int src1 = src0 + 16;
    const bool hi = (g >> 1) != 0;
#pragma unroll
    for (int cc = 0; cc < 2; ++cc) {
      u32 a0 = __shfl(w[cc * 2][0], src0, 64), b0 = __shfl(w[cc * 2 + 1][0], src0, 64);
      u32 a1 = __shfl(w[cc * 2][1], src0, 64), b1 = __shfl(w[cc * 2 + 1][1], src0, 64);
      u32 a2 = __shfl(w[cc * 2][0], src1, 64), b2 = __shfl(w[cc * 2 + 1][0], src1, 64);
      u32 a3 = __shfl(w[cc * 2][1], src1, 64), b3 = __shfl(w[cc * 2 + 1][1], src1, 64);
      union { u32 u[4]; bf16x8 v; } pf;
      pf.u[0] = hi ? b0 : a0;
      pf.u[1] = hi ? b1 : a1;
      pf.u[2] = hi ? b2 : a2;
      pf.u[3] = hi ? b3 : a3;
      const int mcolByte = (cc * 32 + g * 8) * 2;
#pragma unroll
      for (int dt = 0; dt < 16; ++dt) {
        const int row = dt * 16 + fr;
        bf16x8 av = *(const bf16x8*)((const char*)lv + ((row * 128 + mcolByte) ^ ((row & 7) << 4)));
        racc[dt] = __builtin_amdgcn_mfma_f32_16x16x32_bf16(av, pf.v, racc[dt], 0, 0, 0);
      }
    }
  }

  // epilogue: normalize, transpose r'[d][n] -> r[n][d] via LDS, coalesced store to cat
  __syncthreads();
  u16* lt = smem + (size_t)wave * (16 * 264);   // per-wave [16 n][264 d-padded]
  const float inv = 1.f / lrow;
#pragma unroll
  for (int dt = 0; dt < 16; ++dt) {
    u32 w0 = (u32)f2bf(racc[dt][0] * inv) | ((u32)f2bf(racc[dt][1] * inv) << 16);
    u32 w1 = (u32)f2bf(racc[dt][2] * inv) | ((u32)f2bf(racc[dt][3] * inv) << 16);
    *(u32*)(lt + fr * 264 + dt * 16 + g * 4) = w0;
    *(u32*)(lt + fr * 264 + dt * 16 + g * 4 + 2) = w1;
  }
  __syncthreads();
#pragma unroll
  for (int p = 0; p < 8; ++p) {
    const int c2 = p * 64 + lane;
    const int row = c2 >> 5, ch = c2 & 31;
    uint4 val = *(const uint4*)(lt + row * 264 + ch * 8);
    *(uint4*)(cat + (size_t)(n0 + row) * (H_ * D_) + (size_t)h * D_ + ch * 8) = val;
  }
}

// ---------------- host launcher ----------------
extern "C" void kernel_launch(void* const* d_in, const int* in_sizes, int n_in,
                              void* d_out, int out_size, void* d_ws, size_t ws_size,
                              hipStream_t stream) {
  const float* thisf = (const float*)d_in[0];
  const float* thatf = (const float*)d_in[1];
  const void* maskp = (const void*)d_in[2];
  const float* Wq = (const float*)d_in[3];
  const float* bq = (const float*)d_in[4];
  const float* Wk = (const float*)d_in[5];
  const float* bk = (const float*)d_in[6];
  const float* Wv = (const float*)d_in[7];
  const float* bv = (const float*)d_in[8];
  const float* Wo = (const float*)d_in[9];
  const float* bo = (const float*)d_in[10];
  float* outp = (float*)d_out;

  char* ws = (char*)d_ws;
  size_t o = 0;
  u16* thisb = (u16*)(ws + o); o += (size_t)N_ * F_ * 2;
  u16* thatb = (u16*)(ws + o); o += (size_t)M_ * F_ * 2;
  u16* wqt = (u16*)(ws + o); o += (size_t)H_ * D_ * F_ * 2;
  u16* wkt = (u16*)(ws + o); o += (size_t)H_ * D_ * F_ * 2;
  u16* wvt = (u16*)(ws + o); o += (size_t)H_ * D_ * F_ * 2;
  u16* wot = (u16*)(ws + o); o += (size_t)F_ * 2 * F_ * 2;
  u16* qb = (u16*)(ws + o); o += (size_t)H_ * N_ * D_ * 2;
  u16* kb = (u16*)(ws + o); o += (size_t)H_ * M_ * D_ * 2;
  u16* vb = (u16*)(ws + o); o += (size_t)H_ * M_ * D_ * 2;
  u16* vtb = (u16*)(ws + o); o += (size_t)H_ * D_ * M_ * 2;
  u16* catb = (u16*)(ws + o); o += (size_t)N_ * 2 * F_ * 2;
  u64* mbits = (u64*)(ws + o); o += (size_t)N_ * M_ / 8;
  u32* mflag = (u32*)(ws + o); o += 256;
  (void)ws_size; (void)in_sizes; (void)n_in; (void)out_size;

  // 0) mask dtype detect + bit-pack (robust to int32 or int8/bool delivery)
  k_mask_detect<<<dim3(1), dim3(64), 0, stream>>>((const u32*)maskp, mflag);
  k_mask_pack<<<dim3(N_ * M_ / 64 / 256), dim3(256), 0, stream>>>(maskp, mflag, mbits);

  // 1) dtype conversions
  k_f32_to_bf16<<<dim3(N_ * F_ / 4 / 256), dim3(256), 0, stream>>>(thisf, thisb, N_ * F_ / 4);
  k_f32_to_bf16<<<dim3(M_ * F_ / 4 / 256), dim3(256), 0, stream>>>(thatf, thatb, M_ * F_ / 4);
  k_transpose_f32_bf16<<<dim3(F_ / 32, D_ / 32, H_), dim3(256), 0, stream>>>(Wq, wqt, F_, D_);
  k_transpose_f32_bf16<<<dim3(F_ / 32, D_ / 32, H_), dim3(256), 0, stream>>>(Wk, wkt, F_, D_);
  k_transpose_f32_bf16<<<dim3(F_ / 32, D_ / 32, H_), dim3(256), 0, stream>>>(Wv, wvt, F_, D_);
  k_transpose_f32_bf16<<<dim3(2 * F_ / 32, F_ / 32, 1), dim3(256), 0, stream>>>(Wo, wot, 2 * F_, F_);

  // 2) projections: q = this*Wq+bq, k = that*Wk+bk, v = that*Wv+bv   (bf16 out)
  k_gemm_nt<0><<<dim3(N_ / 128, D_ / 128, H_), dim3(256), 0, stream>>>(
      thisb, wqt, bq, nullptr, qb, nullptr, F_, F_, F_, D_,
      (size_t)0, (size_t)D_ * F_, (size_t)D_, (size_t)N_ * D_);
  k_gemm_nt<0><<<dim3(M_ / 128, D_ / 128, H_), dim3(256), 0, stream>>>(
      thatb, wkt, bk, nullptr, kb, nullptr, F_, F_, F_, D_,
      (size_t)0, (size_t)D_ * F_, (size_t)D_, (size_t)M_ * D_);
  k_gemm_nt<0><<<dim3(M_ / 128, D_ / 128, H_), dim3(256), 0, stream>>>(
      thatb, wvt, bv, nullptr, vb, nullptr, F_, F_, F_, D_,
      (size_t)0, (size_t)D_ * F_, (size_t)D_, (size_t)M_ * D_);

  // 3) v -> v^T per head for K-contiguous PV reads
  k_transpose_bf16<<<dim3(M_ / 32, D_ / 32, H_), dim3(256), 0, stream>>>(vb, vtb, M_, D_);

  // 4) flash attention -> cat [N][H*D] bf16
  k_attn<<<dim3(N_ / 64, H_), dim3(256), 0, stream>>>(qb, kb, vtb, mbits, catb);

  // 5) out = cat @ Wo + bo + this   (f32 out)
  k_gemm_nt<1><<<dim3(N_ / 128, F_ / 128, 1), dim3(256), 0, stream>>>(
      catb, wot, bo, thisf, nullptr, outp, 2 * F_, 2 * F_, 2 * F_, F_,
      (size_t)0, (size_t)0, (size_t)0, (size_t)0);
}